// Round 1
// baseline (215.706 us; speedup 1.0000x reference)
//
#include <hip/hip_runtime.h>
#include <math.h>

// Cost weights / focal params (match reference)
#define W_CLASS 1.0f
#define W_BBOX  5.0f
#define W_GIOU  2.0f
#define F_ALPHA 0.25f
#define F_EPS   1e-8f

typedef float f2 __attribute__((ext_vector_type(2)));

// v_rcp_f32 + one Newton step -> ~0.5 ulp, replaces the ~12-instr IEEE divide
__device__ __forceinline__ float fast_rcp(float x) {
    float r = __builtin_amdgcn_rcpf(x);
    r = fmaf(fmaf(-x, r, 1.0f), r, r);
    return r;
}

// Phase 1: per-row softmax over C=128 logits + focal class-cost table.
// delta[n*128 + c] = pos_cost(n,c) - neg_cost(n,c)
// One wave (64 lanes) per row, float2 per lane, 4 rows per 256-thread block.
__global__ __launch_bounds__(256)
void class_cost_kernel(const float* __restrict__ logits,
                       float* __restrict__ delta) {
    const int wave = threadIdx.x >> 6;
    const int lane = threadIdx.x & 63;
    const int n = blockIdx.x * 4 + wave;

    f2 x = ((const f2*)(logits + (size_t)n * 128))[lane];

    // wave max-reduce
    float m = fmaxf(x.x, x.y);
    #pragma unroll
    for (int off = 32; off > 0; off >>= 1)
        m = fmaxf(m, __shfl_xor(m, off));

    float e0 = __expf(x.x - m);
    float e1 = __expf(x.y - m);
    float s = e0 + e1;
    #pragma unroll
    for (int off = 32; off > 0; off >>= 1)
        s += __shfl_xor(s, off);
    float inv = fast_rcp(s);

    float p0 = e0 * inv;
    float p1 = e1 * inv;

    // focal: pos = a*(1-p)^2*(-log(p+eps)); neg = (1-a)*p^2*(-log(1-p+eps))
    float omp0 = 1.0f - p0;
    float omp1 = 1.0f - p1;
    float d0 = F_ALPHA * omp0 * omp0 * (-__logf(p0 + F_EPS))
             - (1.0f - F_ALPHA) * p0 * p0 * (-__logf(omp0 + F_EPS));
    float d1 = F_ALPHA * omp1 * omp1 * (-__logf(p1 + F_EPS))
             - (1.0f - F_ALPHA) * p1 * p1 * (-__logf(omp1 + F_EPS));

    f2 o; o.x = d0; o.y = d1;
    ((f2*)(delta + (size_t)n * 128))[lane] = o;
}

// Phase 2: full cost matrix. One thread per PAIR of targets (t0, t0+1),
// ROWS_PER_BLOCK rows per block. float2 stores (8B/lane), rcp-based GIoU:
//   giou = inter/uni - (earea-uni)/earea = inter*rcp(uni) + uni*rcp(earea) - 1
#define ROWS_PER_BLOCK 4

__device__ __forceinline__ float cost_el(
    float pcx, float pcy, float pw, float ph,
    float px0, float py0, float px1, float py1, float parea,
    float tcx, float tcy, float tw, float th,
    float tx0, float ty0, float tx1, float ty1, float tarea,
    float d)
{
    // L1 cost on raw cxcywh
    float cb = fabsf(pcx - tcx) + fabsf(pcy - tcy)
             + fabsf(pw - tw) + fabsf(ph - th);

    // intersection
    float ix0 = fmaxf(px0, tx0), iy0 = fmaxf(py0, ty0);
    float ix1 = fminf(px1, tx1), iy1 = fminf(py1, ty1);
    float iw = fmaxf(ix1 - ix0, 0.0f), ih = fmaxf(iy1 - iy0, 0.0f);
    float inter = iw * ih;
    float uni = parea + tarea - inter;

    // enclosing box
    float ex0 = fminf(px0, tx0), ey0 = fminf(py0, ty0);
    float ex1 = fmaxf(px1, tx1), ey1 = fmaxf(py1, ty1);
    float earea = (ex1 - ex0) * (ey1 - ey0);

    float giou = fmaf(inter, fast_rcp(uni), uni * fast_rcp(earea)) - 1.0f;

    return fmaf(W_BBOX, cb, fmaf(-W_GIOU, giou, W_CLASS * d));
}

__global__ __launch_bounds__(256)
void cost_kernel(const float4* __restrict__ pred_boxes,   // [N,4] cxcywh
                 const float4* __restrict__ tgt_bbox,     // [T,4] cxcywh
                 const int* __restrict__ tgt_ids,         // [T]
                 const float* __restrict__ delta,         // [N,128]
                 float* __restrict__ out,                 // [N,T]
                 int T) {
    const int t0 = (blockIdx.x * blockDim.x + threadIdx.x) * 2;
    if (t0 >= T) return;   // whole-wave-uniform tail exit (no barriers below)

    const float4 tbA = tgt_bbox[t0];
    const float4 tbB = tgt_bbox[t0 + 1];
    const int idA = tgt_ids[t0];
    const int idB = tgt_ids[t0 + 1];

    // tgt xyxy + area (hoisted out of the row loop)
    const float ax0 = tbA.x - 0.5f * tbA.z, ay0 = tbA.y - 0.5f * tbA.w;
    const float ax1 = tbA.x + 0.5f * tbA.z, ay1 = tbA.y + 0.5f * tbA.w;
    const float areaA = (ax1 - ax0) * (ay1 - ay0);

    const float bx0 = tbB.x - 0.5f * tbB.z, by0 = tbB.y - 0.5f * tbB.w;
    const float bx1 = tbB.x + 0.5f * tbB.z, by1 = tbB.y + 0.5f * tbB.w;
    const float areaB = (bx1 - bx0) * (by1 - by0);

    const int n0 = blockIdx.y * ROWS_PER_BLOCK;

    #pragma unroll
    for (int r = 0; r < ROWS_PER_BLOCK; ++r) {
        const int n = n0 + r;
        const float4 pb = pred_boxes[n];   // uniform across block
        const float px0 = pb.x - 0.5f * pb.z, py0 = pb.y - 0.5f * pb.w;
        const float px1 = pb.x + 0.5f * pb.z, py1 = pb.y + 0.5f * pb.w;
        const float parea = (px1 - px0) * (py1 - py0);

        const float* drow = delta + n * 128;
        const float dA = drow[idA];        // 4B gather within 512B row (L1)
        const float dB = drow[idB];

        float cA = cost_el(pb.x, pb.y, pb.z, pb.w,
                           px0, py0, px1, py1, parea,
                           tbA.x, tbA.y, tbA.z, tbA.w,
                           ax0, ay0, ax1, ay1, areaA, dA);
        float cB = cost_el(pb.x, pb.y, pb.z, pb.w,
                           px0, py0, px1, py1, parea,
                           tbB.x, tbB.y, tbB.z, tbB.w,
                           bx0, by0, bx1, by1, areaB, dB);

        f2 o; o.x = cA; o.y = cB;
        // output is write-once, zero-reuse: bypass L2 (keep delta/tgt resident)
        __builtin_nontemporal_store(o, (f2*)(out + (size_t)n * T + t0));
    }
}

extern "C" void kernel_launch(void* const* d_in, const int* in_sizes, int n_in,
                              void* d_out, int out_size, void* d_ws, size_t ws_size,
                              hipStream_t stream) {
    const float* pred_logits = (const float*)d_in[0];   // [16,900,128] f32
    const float* pred_boxes  = (const float*)d_in[1];   // [16,900,4]  f32
    const int*   tgt_ids     = (const int*)d_in[2];     // [3200] int32
    const float* tgt_bbox    = (const float*)d_in[3];   // [3200,4] f32
    float* out = (float*)d_out;
    float* delta = (float*)d_ws;                        // [14400,128] f32 = 7.4 MB

    const int N = in_sizes[1] / 4;   // bs*Q = 14400
    const int T = in_sizes[2];       // 3200

    // Phase 1: class-cost table (one wave per row, 4 rows/block)
    class_cost_kernel<<<N / 4, 256, 0, stream>>>(pred_logits, delta);

    // Phase 2: full cost matrix, 2 targets/thread
    dim3 grid((T / 2 + 255) / 256, N / ROWS_PER_BLOCK);
    cost_kernel<<<grid, 256, 0, stream>>>(
        (const float4*)pred_boxes, (const float4*)tgt_bbox, tgt_ids, delta, out, T);
}